// Round 6
// baseline (518.147 us; speedup 1.0000x reference)
//
#include <hip/hip_runtime.h>
#include <hip/hip_bf16.h>
#include <stdint.h>

#define DEVFN static __device__ __forceinline__

typedef __bf16 bf16x8 __attribute__((ext_vector_type(8)));
typedef float f32x4 __attribute__((ext_vector_type(4)));

DEVFN unsigned short f2bf(float f) {
  unsigned int u = __float_as_uint(f);
  u += 0x7FFFu + ((u >> 16) & 1u);
  return (unsigned short)(u >> 16);
}

DEVFN float softplus_f(float s) {
  return fmaxf(s, 0.0f) + log1pf(__expf(-fabsf(s)));
}

DEVFN void load_lds16(const void* g, void* l) {
  __builtin_amdgcn_global_load_lds(
      (const __attribute__((address_space(1))) void*)g,
      (__attribute__((address_space(3))) void*)l, 16, 0, 0);
}

// ---------------- elementwise: A = mW + softplus(sW)*zW  (fp32 -> bf16) ----
__global__ void fuse_w_kernel(const float* __restrict__ m, const float* __restrict__ s,
                              const float* __restrict__ z, unsigned short* __restrict__ o,
                              int n4) {
  int stride = gridDim.x * blockDim.x;
  for (int i = blockIdx.x * blockDim.x + threadIdx.x; i < n4; i += stride) {
    float4 mv = reinterpret_cast<const float4*>(m)[i];
    float4 sv = reinterpret_cast<const float4*>(s)[i];
    float4 zv = reinterpret_cast<const float4*>(z)[i];
    ushort4 ov;
    ov.x = f2bf(fmaf(softplus_f(sv.x), zv.x, mv.x));
    ov.y = f2bf(fmaf(softplus_f(sv.y), zv.y, mv.y));
    ov.z = f2bf(fmaf(softplus_f(sv.z), zv.z, mv.z));
    ov.w = f2bf(fmaf(softplus_f(sv.w), zv.w, mv.w));
    reinterpret_cast<ushort4*>(o)[i] = ov;
  }
}

// ---------------- all three biases in one launch ---------------------------
__global__ void bias_all_kernel(const float* __restrict__ mb0, const float* __restrict__ sb0,
                                const float* __restrict__ zb0,
                                const float* __restrict__ mb1, const float* __restrict__ sb1,
                                const float* __restrict__ zb1,
                                const float* __restrict__ mb2, const float* __restrict__ sb2,
                                const float* __restrict__ zb2,
                                float* __restrict__ b0, float* __restrict__ b1,
                                float* __restrict__ b2) {
  int i = blockIdx.x * blockDim.x + threadIdx.x;
  if (i < 4096) {
    b0[i] = fmaf(softplus_f(sb0[i]), zb0[i], mb0[i]);
  } else if (i < 8192) {
    int k = i - 4096;
    b1[k] = fmaf(softplus_f(sb1[k]), zb1[k], mb1[k]);
  } else if (i < 9216) {
    int k = i - 8192;
    b2[k] = fmaf(softplus_f(sb2[k]), zb2[k], mb2[k]);
  }
}

// ---------------- x fp32 -> bf16 -------------------------------------------
__global__ void xconv_kernel(const float* __restrict__ x, unsigned short* __restrict__ o,
                             int n4) {
  int stride = gridDim.x * blockDim.x;
  for (int i = blockIdx.x * blockDim.x + threadIdx.x; i < n4; i += stride) {
    float4 v = reinterpret_cast<const float4*>(x)[i];
    ushort4 ov;
    ov.x = f2bf(v.x); ov.y = f2bf(v.y); ov.z = f2bf(v.z); ov.w = f2bf(v.w);
    reinterpret_cast<ushort4*>(o)[i] = ov;
  }
}

// ===========================================================================
// 8-phase GEMM (m201-template port). BM=256, BK=64, BN=WN*64.
// 8 waves: (8/WN) M-rows x WN N-cols; per wave MFM=2*WN M-frags x 4 N-frags.
//
// K-tile kt (buf r=kt&1) = 4 phases; phase = { ds_reads (8 or 4, swizzled)
//   || stage ONE half of tile kt+1 into buf r^1 ; [counted vmcnt at ph2/ph4]
//   -> s_barrier -> lgkmcnt(0) -> sched_barrier -> setprio(1) ->
//   HM*4 MFMA -> setprio(0) -> s_barrier }.
// ph1: s=0 fh=0 (reads B[s0] 4 + A[lo,s0] HM), stage A'(h0)
// ph2: s=0 fh=1 (A[hi,s0] HM),                stage B'(h0), vmcnt
// ph3: s=1 fh=0 (B[s1] 4 + A[lo,s1]),         stage A'(h1)
// ph4: s=1 fh=1 (A[hi,s1]),                   stage B'(h1), vmcnt
//
// Race-freedom is structural: reads touch buf r, stage writes touch buf r^1
// (ring-2, lead exactly 1 tile). vmcnt ledger (per wave, loads/half: A=2,
// B=BLD): halves staged in kt = {A0',B0',A1',B1'}; A0',B0' first read at
// ph1(kt+1) -> vmcnt(2+BLD) at ph4(kt) leaves only {A1',B1'} in flight;
// A1',B1' first read at ph3(kt+1) -> vmcnt(2+BLD) at ph2(kt+1) (at that
// point in-flight = {A1',B1'} + {A0'',B0''}). Last tile: vmcnt(0) at ph2
// (counted form would be trivially satisfied without guaranteeing landing).
//
// Swizzle (verified 0 conflicts R4/R5): 64B-row slots [256][32k]; read
// chunk kg^((l15>>1)&3); stage pre-swizzles the per-lane GLOBAL source
// chunk (cc^((rS>>1)&3)), LDS dest linear (global_load_lds requirement).
// ===========================================================================
template <int WN, int RELU, int OUTBF16>
__global__ __launch_bounds__(512, 2) void gemm8p_kernel(
    const unsigned short* __restrict__ X, const unsigned short* __restrict__ W,
    const float* __restrict__ bias, void* __restrict__ out,
    int M, int N, int K) {
  constexpr int MFM = (WN == 4) ? 8 : 4;   // M-frags per wave
  constexpr int HM  = MFM / 2;             // frags per phase
  constexpr int BN  = WN * 64;
  constexpr int BSB = BN * 64;             // B half-slot bytes (16K or 8K)
  constexpr int BLD = (WN == 4) ? 2 : 1;   // B gloads per thread per half
  constexpr int VW  = 2 + BLD;             // counted vmcnt value
  __shared__ __align__(16) char lds[65536 + 4 * BSB];

  const int tid  = threadIdx.x;
  const int lane = tid & 63;
  const int wv   = tid >> 6;
  const int wm   = wv / WN;
  const int wn   = wv % WN;
  const int row0 = blockIdx.y * 256;
  const int col0 = blockIdx.x * BN;
  const size_t ldb = (size_t)K * 2;

  // staging source (pre-swizzled chunk, verified R4)
  const int ct  = wv * 64 + lane;          // 0..511
  const int rS  = ct >> 2;                 // 0..127
  const int ccS = (ct & 3) ^ ((rS >> 1) & 3);
  const char* srcA = (const char*)X + (size_t)(row0 + rS) * ldb + ccS * 16;
  const char* srcB = (const char*)W + (size_t)(col0 + rS) * ldb + ccS * 16;

  auto stageA = [&](int kt, int h) {       // 16KB: 256 rows x 32 k
    char* d = lds + (((kt & 1) * 2 + h) << 14) + wv * 1024;
    const char* s = srcA + (size_t)kt * 128 + h * 64;
    load_lds16(s, d);
    load_lds16(s + 128 * ldb, d + 8192);   // rows +128: swizzle invariant
  };
  auto stageB = [&](int kt, int h) {       // BN rows x 32 k
    char* d = lds + 65536 + ((kt & 1) * 2 + h) * BSB + wv * 1024;
    const char* s = srcB + (size_t)kt * 128 + h * 64;
    load_lds16(s, d);
    if constexpr (WN == 4) load_lds16(s + 128 * ldb, d + 8192);
  };

  // fragment addressing (swizzled kg, lane-constant)
  const int l15 = lane & 15;
  const int kg  = lane >> 4;
  const int kgs = kg ^ ((l15 >> 1) & 3);
  const int aBase = (wm * (MFM * 16) + l15) * 64 + kgs * 16;
  const int bBase = (wn * 64 + l15) * 64 + kgs * 16;

  auto readA = [&](int kt, int s, int fh, bf16x8 (&a)[HM]) {
    const char* base = lds + (((kt & 1) * 2 + s) << 14) + aBase + fh * (HM * 1024);
#pragma unroll
    for (int i = 0; i < HM; ++i)
      a[i] = *(const bf16x8*)(base + i * 1024);
  };
  auto readB = [&](int kt, int s, bf16x8 (&b)[4]) {
    const char* base = lds + 65536 + ((kt & 1) * 2 + s) * BSB + bBase;
#pragma unroll
    for (int j = 0; j < 4; ++j)
      b[j] = *(const bf16x8*)(base + j * 1024);
  };

  f32x4 acc[MFM][4];
#pragma unroll
  for (int i = 0; i < MFM; ++i)
#pragma unroll
    for (int j = 0; j < 4; ++j)
      acc[i][j] = (f32x4){0.f, 0.f, 0.f, 0.f};

#define PHASE_TAIL(FH)                                                        \
  __builtin_amdgcn_s_barrier();                                               \
  asm volatile("s_waitcnt lgkmcnt(0)" ::: "memory");                          \
  __builtin_amdgcn_sched_barrier(0);                                          \
  __builtin_amdgcn_s_setprio(1);                                              \
  _Pragma("unroll")                                                           \
  for (int i = 0; i < HM; ++i)                                                \
    _Pragma("unroll")                                                         \
    for (int j = 0; j < 4; ++j)                                               \
      acc[(FH) * HM + i][j] = __builtin_amdgcn_mfma_f32_16x16x32_bf16(        \
          a[i], b[j], acc[(FH) * HM + i][j], 0, 0, 0);                        \
  __builtin_amdgcn_s_setprio(0);                                              \
  __builtin_amdgcn_s_barrier();

  const int nt = K >> 6;

  // prologue: stage tile 0 fully, publish
  stageA(0, 0); stageB(0, 0); stageA(0, 1); stageB(0, 1);
  asm volatile("s_waitcnt vmcnt(0)" ::: "memory");
  __builtin_amdgcn_s_barrier();

  for (int kt = 0; kt < nt; ++kt) {
    const bool last = (kt + 1 >= nt);
    bf16x8 a[HM], b[4];

    // ---- phase 1: s=0, fh=0 ----
    readB(kt, 0, b); readA(kt, 0, 0, a);
    if (!last) stageA(kt + 1, 0);
    PHASE_TAIL(0)

    // ---- phase 2: s=0, fh=1 ----
    readA(kt, 0, 1, a);
    if (!last) stageB(kt + 1, 0);
    if (last) { asm volatile("s_waitcnt vmcnt(0)" ::: "memory"); }
    else      { asm volatile("s_waitcnt vmcnt(%0)" :: "i"(VW) : "memory"); }
    PHASE_TAIL(1)

    // ---- phase 3: s=1, fh=0 ----
    readB(kt, 1, b); readA(kt, 1, 0, a);
    if (!last) stageA(kt + 1, 1);
    PHASE_TAIL(0)

    // ---- phase 4: s=1, fh=1 ----
    readA(kt, 1, 1, a);
    if (!last) {
      stageB(kt + 1, 1);
      asm volatile("s_waitcnt vmcnt(%0)" :: "i"(VW) : "memory");
    }
    PHASE_TAIL(1)
  }
#undef PHASE_TAIL

  // ---- epilogue: bias + optional ReLU ----
  float bv[4];
#pragma unroll
  for (int j = 0; j < 4; ++j) bv[j] = bias[col0 + wn * 64 + j * 16 + l15];

  const int rbase = row0 + wm * (MFM * 16) + kg * 4;
  const int cbase = col0 + wn * 64 + l15;
#pragma unroll
  for (int i = 0; i < MFM; ++i) {
#pragma unroll
    for (int j = 0; j < 4; ++j) {
#pragma unroll
      for (int r = 0; r < 4; ++r) {
        float v = acc[i][j][r] + bv[j];
        if (RELU) v = fmaxf(v, 0.0f);
        const size_t idx = (size_t)(rbase + i * 16 + r) * N + (cbase + j * 16);
        if (OUTBF16) ((unsigned short*)out)[idx] = f2bf(v);
        else         ((float*)out)[idx] = v;
      }
    }
  }
}

// ---------------------------------------------------------------------------
extern "C" void kernel_launch(void* const* d_in, const int* in_sizes, int n_in,
                              void* d_out, int out_size, void* d_ws, size_t ws_size,
                              hipStream_t stream) {
  const float* x   = (const float*)d_in[0];
  const float* mW0 = (const float*)d_in[1];
  const float* sW0 = (const float*)d_in[2];
  const float* zW0 = (const float*)d_in[3];
  const float* mb0 = (const float*)d_in[4];
  const float* sb0 = (const float*)d_in[5];
  const float* zb0 = (const float*)d_in[6];
  const float* mW1 = (const float*)d_in[7];
  const float* sW1 = (const float*)d_in[8];
  const float* zW1 = (const float*)d_in[9];
  const float* mb1 = (const float*)d_in[10];
  const float* sb1 = (const float*)d_in[11];
  const float* zb1 = (const float*)d_in[12];
  const float* mW2 = (const float*)d_in[13];
  const float* sW2 = (const float*)d_in[14];
  const float* zW2 = (const float*)d_in[15];
  const float* mb2 = (const float*)d_in[16];
  const float* sb2 = (const float*)d_in[17];
  const float* zb2 = (const float*)d_in[18];

  char* ws = (char*)d_ws;
  size_t off = 0;
  auto alloc = [&](size_t bytes) {
    char* p = ws + off;
    off += (bytes + 255) & ~(size_t)255;
    return p;
  };
  unsigned short* xb = (unsigned short*)alloc(8192ull * 1024 * 2);
  unsigned short* A0 = (unsigned short*)alloc(4096ull * 1024 * 2);
  unsigned short* A1 = (unsigned short*)alloc(4096ull * 4096 * 2);
  unsigned short* A2 = (unsigned short*)alloc(1024ull * 4096 * 2);
  unsigned short* h1 = (unsigned short*)alloc(8192ull * 4096 * 2);
  unsigned short* h2 = (unsigned short*)alloc(8192ull * 4096 * 2);
  float* b0 = (float*)alloc(4096 * 4);
  float* b1 = (float*)alloc(4096 * 4);
  float* b2 = (float*)alloc(1024 * 4);

  fuse_w_kernel<<<2048, 256, 0, stream>>>(mW0, sW0, zW0, A0, (4096 * 1024) / 4);
  fuse_w_kernel<<<2048, 256, 0, stream>>>(mW1, sW1, zW1, A1, (4096 * 4096) / 4);
  fuse_w_kernel<<<2048, 256, 0, stream>>>(mW2, sW2, zW2, A2, (1024 * 4096) / 4);
  xconv_kernel<<<2048, 256, 0, stream>>>(x, xb, (8192 * 1024) / 4);
  bias_all_kernel<<<36, 256, 0, stream>>>(mb0, sb0, zb0, mb1, sb1, zb1,
                                          mb2, sb2, zb2, b0, b1, b2);

  // layer 0: [8192,1024] @ [4096,1024]^T -> relu -> h1 bf16   (BN=256)
  dim3 g01(4096 / 256, 8192 / 256);
  gemm8p_kernel<4, 1, 1><<<g01, 512, 0, stream>>>(xb, A0, b0, h1, 8192, 4096, 1024);
  // layer 1: [8192,4096] @ [4096,4096]^T -> relu -> h2 bf16   (BN=256)
  gemm8p_kernel<4, 1, 1><<<g01, 512, 0, stream>>>(h1, A1, b1, h2, 8192, 4096, 4096);
  // layer 2: [8192,4096] @ [1024,4096]^T -> d_out fp32        (BN=128, 256 blocks)
  dim3 g2(1024 / 128, 8192 / 256);
  gemm8p_kernel<2, 0, 0><<<g2, 512, 0, stream>>>(h2, A2, b2, d_out, 8192, 1024, 4096);
}

// Round 7
// 484.637 us; speedup vs baseline: 1.0691x; 1.0691x over previous
//
#include <hip/hip_runtime.h>
#include <hip/hip_bf16.h>
#include <stdint.h>

#define DEVFN static __device__ __forceinline__

typedef __bf16 bf16x8 __attribute__((ext_vector_type(8)));
typedef float f32x4 __attribute__((ext_vector_type(4)));

DEVFN unsigned short f2bf(float f) {
  unsigned int u = __float_as_uint(f);
  u += 0x7FFFu + ((u >> 16) & 1u);
  return (unsigned short)(u >> 16);
}

DEVFN float softplus_f(float s) {
  return fmaxf(s, 0.0f) + log1pf(__expf(-fabsf(s)));
}

DEVFN void load_lds16(const void* g, void* l) {
  __builtin_amdgcn_global_load_lds(
      (const __attribute__((address_space(1))) void*)g,
      (__attribute__((address_space(3))) void*)l, 16, 0, 0);
}

// ---------------- elementwise: A = mW + softplus(sW)*zW  (fp32 -> bf16) ----
__global__ void fuse_w_kernel(const float* __restrict__ m, const float* __restrict__ s,
                              const float* __restrict__ z, unsigned short* __restrict__ o,
                              int n4) {
  int stride = gridDim.x * blockDim.x;
  for (int i = blockIdx.x * blockDim.x + threadIdx.x; i < n4; i += stride) {
    float4 mv = reinterpret_cast<const float4*>(m)[i];
    float4 sv = reinterpret_cast<const float4*>(s)[i];
    float4 zv = reinterpret_cast<const float4*>(z)[i];
    ushort4 ov;
    ov.x = f2bf(fmaf(softplus_f(sv.x), zv.x, mv.x));
    ov.y = f2bf(fmaf(softplus_f(sv.y), zv.y, mv.y));
    ov.z = f2bf(fmaf(softplus_f(sv.z), zv.z, mv.z));
    ov.w = f2bf(fmaf(softplus_f(sv.w), zv.w, mv.w));
    reinterpret_cast<ushort4*>(o)[i] = ov;
  }
}

// ---------------- all three biases in one launch ---------------------------
__global__ void bias_all_kernel(const float* __restrict__ mb0, const float* __restrict__ sb0,
                                const float* __restrict__ zb0,
                                const float* __restrict__ mb1, const float* __restrict__ sb1,
                                const float* __restrict__ zb1,
                                const float* __restrict__ mb2, const float* __restrict__ sb2,
                                const float* __restrict__ zb2,
                                float* __restrict__ b0, float* __restrict__ b1,
                                float* __restrict__ b2) {
  int i = blockIdx.x * blockDim.x + threadIdx.x;
  if (i < 4096) {
    b0[i] = fmaf(softplus_f(sb0[i]), zb0[i], mb0[i]);
  } else if (i < 8192) {
    int k = i - 4096;
    b1[k] = fmaf(softplus_f(sb1[k]), zb1[k], mb1[k]);
  } else if (i < 9216) {
    int k = i - 8192;
    b2[k] = fmaf(softplus_f(sb2[k]), zb2[k], mb2[k]);
  }
}

// ---------------- x fp32 -> bf16 -------------------------------------------
__global__ void xconv_kernel(const float* __restrict__ x, unsigned short* __restrict__ o,
                             int n4) {
  int stride = gridDim.x * blockDim.x;
  for (int i = blockIdx.x * blockDim.x + threadIdx.x; i < n4; i += stride) {
    float4 v = reinterpret_cast<const float4*>(x)[i];
    ushort4 ov;
    ov.x = f2bf(v.x); ov.y = f2bf(v.y); ov.z = f2bf(v.z); ov.w = f2bf(v.w);
    reinterpret_cast<ushort4*>(o)[i] = ov;
  }
}

// ===========================================================================
// Pipelined GEMM, BM=256, BK=32, BN = WN*64 (WN=4 -> 256, WN=2 -> 128).
// 8 waves as (8/WN) M-rows x WN N-cols. 1-D grid + bijective XCD swizzle (T1).
//
// R7: R5's register double-buffer pipeline, with the per-tile lgkm pins and
// sched_barriers REMOVED. The ds_reads are plain loads: the compiler tracks
// the frag->MFMA dependencies and emits fine-grained counted lgkmcnt, so
// early MFMAs issue while later fragment reads drain (the overlap my
// explicit lgkmcnt(0)+sched_barrier(0) walls were serializing away;
// m141-class regression). Only the cooperative-staging handshake keeps
// explicit sync: counted vmcnt + s_barrier once per K-tile. The "memory"
// clobber on the vmcnt asm prevents the next tile's ds_reads from hoisting
// above the barrier.
//
// Ring-of-4 slots, stage lead 3 tiles: at iter t -- reads touch (t+1)&3,
// MFMA source t&3, landing (t+2)&3, staging (t+3)&3: all distinct.
// vmcnt ledger: only vmem ops in-loop are LPT global_load_lds per tile;
// vmcnt(LPT) at end of iter t leaves only stage(t+3) in flight => t+2
// landed; barrier publishes. Reads of t+1 (iter t) were published at end
// of iter t-1. Once t+3 >= nt nothing more is staged -> vmcnt(0).
//
// T2 swizzle (verified 0 conflicts R4-R6): 16B-chunk cc ^= (row>>1)&3 on
// the per-lane GLOBAL source at stage (LDS dest linear); kg ^= (l15>>1)&3
// on the fragment read (lane-constant, folds into static index).
// ===========================================================================
template <int WN, int RELU, int OUTBF16>
__global__ __launch_bounds__(512, 2) void gemm_pipe_kernel(
    const unsigned short* __restrict__ X, const unsigned short* __restrict__ W,
    const float* __restrict__ bias, void* __restrict__ out,
    int M, int N, int K, int gx) {
  constexpr int BN  = WN * 64;         // 256 or 128
  constexpr int MF  = 2 * WN;          // A-frags per wave (8 or 4)
  constexpr int LPT = (WN == 4) ? 4 : 3;  // global_load_lds per tile per thread
  constexpr int BS  = BN * 32;         // B slot size, ushorts
  __shared__ __align__(16) unsigned short lds[32768 + 4 * BS];

  // T1: bijective XCD swizzle (grid % 8 == 0 for all launches here)
  const int nwg = gridDim.x;
  const int bid = blockIdx.x;
  const int nid = (bid & 7) * (nwg >> 3) + (bid >> 3);
  const int bx  = nid % gx;
  const int by  = nid / gx;

  const int tid  = threadIdx.x;
  const int lane = tid & 63;
  const int wv   = tid >> 6;                 // 0..7
  const int wm   = wv / WN;
  const int wn   = wv % WN;
  const int row0 = by * 256;
  const int col0 = bx * BN;
  const size_t ldb = (size_t)K * 2;

  // staging: chunk c -> row c>>2, chunkcol c&3; source chunkcol pre-swizzled
  const int cA  = wv * 64 + lane;
  const int rS  = cA >> 2;
  const int ccS = (cA & 3) ^ ((rS >> 1) & 3);
  const char* srcA = (const char*)X + (size_t)(row0 + rS) * ldb + ccS * 16;
  const char* srcB = (const char*)W + (size_t)(col0 + rS) * ldb + ccS * 16;
  char* ldsb = (char*)lds;

  auto stageA = [&](int tt) {
    char* d = ldsb + (tt & 3) * 16384 + wv * 1024;
    const char* s = srcA + (size_t)tt * 64;
    load_lds16(s, d);
    load_lds16(s + 128 * ldb, d + 8192);     // rows +128: swizzle invariant
  };
  auto stageB = [&](int tt) {
    char* d = ldsb + 65536 + (tt & 3) * (BS * 2) + wv * 1024;
    const char* s = srcB + (size_t)tt * 64;
    load_lds16(s, d);
    if constexpr (WN == 4) load_lds16(s + 128 * ldb, d + 8192);
  };

  const int l15 = lane & 15;
  const int kg  = lane >> 4;
  const int kgs = kg ^ ((l15 >> 1) & 3);
  const int aIdx = (wm * (32 * WN) + l15) * 32 + kgs * 8;
  const int bIdx = (wn * 64 + l15) * 32 + kgs * 8;

  f32x4 acc[MF][4];
#pragma unroll
  for (int i = 0; i < MF; ++i)
#pragma unroll
    for (int j = 0; j < 4; ++j)
      acc[i][j] = (f32x4){0.f, 0.f, 0.f, 0.f};

  auto readFrags = [&](int tt, bf16x8 (&aF)[MF], bf16x8 (&bF)[4]) {
    const int sa = (tt & 3) * 8192;
    const int sb = 32768 + (tt & 3) * BS;
#pragma unroll
    for (int i = 0; i < MF; ++i) aF[i] = *(const bf16x8*)&lds[sa + aIdx + i * 512];
#pragma unroll
    for (int j = 0; j < 4; ++j)  bF[j] = *(const bf16x8*)&lds[sb + bIdx + j * 512];
  };
  auto mfmaTile = [&](bf16x8 (&aF)[MF], bf16x8 (&bF)[4]) {
    __builtin_amdgcn_s_setprio(1);
#pragma unroll
    for (int i = 0; i < MF; ++i)
#pragma unroll
      for (int j = 0; j < 4; ++j)
        acc[i][j] = __builtin_amdgcn_mfma_f32_16x16x32_bf16(aF[i], bF[j], acc[i][j], 0, 0, 0);
    __builtin_amdgcn_s_setprio(0);
  };

  const int nt = K >> 5;
  bf16x8 aA[MF], bA[4], aB[MF], bB[4];

  // prologue: stage tiles 0,1,2; publish 0,1; preload frags(0)
  stageA(0); stageB(0); stageA(1); stageB(1); stageA(2); stageB(2);
  asm volatile("s_waitcnt vmcnt(%0)" :: "i"(LPT) : "memory");  // t0,t1 landed
  __builtin_amdgcn_s_barrier();
  readFrags(0, aA, bA);

  // body: NO lgkm pins, NO sched_barriers -- compiler schedules frag reads
  // and their waits against the MFMA cluster.
  auto body = [&](int t, bf16x8 (&aCur)[MF], bf16x8 (&bCur)[4],
                  bf16x8 (&aNxt)[MF], bf16x8 (&bNxt)[4]) {
    readFrags(t + 1, aNxt, bNxt);
    if (t + 3 < nt) { stageA(t + 3); stageB(t + 3); }
    mfmaTile(aCur, bCur);
    if (t + 3 < nt) asm volatile("s_waitcnt vmcnt(%0)" :: "i"(LPT) : "memory");
    else            asm volatile("s_waitcnt vmcnt(0)" ::: "memory");
    __builtin_amdgcn_s_barrier();  // publish t+2
  };

  for (int t = 0; t < nt - 2; t += 2) {
    body(t,     aA, bA, aB, bB);
    body(t + 1, aB, bB, aA, bA);
  }
  body(nt - 2, aA, bA, aB, bB);   // reads frags(nt-1); drains staging
  mfmaTile(aB, bB);               // compiler inserts the lgkm wait it needs

  // ---- epilogue: bias + optional ReLU ----
  float bv[4];
#pragma unroll
  for (int j = 0; j < 4; ++j) bv[j] = bias[col0 + wn * 64 + j * 16 + l15];

  const int rbase = row0 + wm * (32 * WN) + kg * 4;
  const int cbase = col0 + wn * 64 + l15;
#pragma unroll
  for (int i = 0; i < MF; ++i) {
#pragma unroll
    for (int j = 0; j < 4; ++j) {
#pragma unroll
      for (int r = 0; r < 4; ++r) {
        float v = acc[i][j][r] + bv[j];
        if (RELU) v = fmaxf(v, 0.0f);
        const size_t idx = (size_t)(rbase + i * 16 + r) * N + (cbase + j * 16);
        if (OUTBF16) ((unsigned short*)out)[idx] = f2bf(v);
        else         ((float*)out)[idx] = v;
      }
    }
  }
}

// ---------------------------------------------------------------------------
extern "C" void kernel_launch(void* const* d_in, const int* in_sizes, int n_in,
                              void* d_out, int out_size, void* d_ws, size_t ws_size,
                              hipStream_t stream) {
  const float* x   = (const float*)d_in[0];
  const float* mW0 = (const float*)d_in[1];
  const float* sW0 = (const float*)d_in[2];
  const float* zW0 = (const float*)d_in[3];
  const float* mb0 = (const float*)d_in[4];
  const float* sb0 = (const float*)d_in[5];
  const float* zb0 = (const float*)d_in[6];
  const float* mW1 = (const float*)d_in[7];
  const float* sW1 = (const float*)d_in[8];
  const float* zW1 = (const float*)d_in[9];
  const float* mb1 = (const float*)d_in[10];
  const float* sb1 = (const float*)d_in[11];
  const float* zb1 = (const float*)d_in[12];
  const float* mW2 = (const float*)d_in[13];
  const float* sW2 = (const float*)d_in[14];
  const float* zW2 = (const float*)d_in[15];
  const float* mb2 = (const float*)d_in[16];
  const float* sb2 = (const float*)d_in[17];
  const float* zb2 = (const float*)d_in[18];

  char* ws = (char*)d_ws;
  size_t off = 0;
  auto alloc = [&](size_t bytes) {
    char* p = ws + off;
    off += (bytes + 255) & ~(size_t)255;
    return p;
  };
  unsigned short* xb = (unsigned short*)alloc(8192ull * 1024 * 2);
  unsigned short* A0 = (unsigned short*)alloc(4096ull * 1024 * 2);
  unsigned short* A1 = (unsigned short*)alloc(4096ull * 4096 * 2);
  unsigned short* A2 = (unsigned short*)alloc(1024ull * 4096 * 2);
  unsigned short* h1 = (unsigned short*)alloc(8192ull * 4096 * 2);
  unsigned short* h2 = (unsigned short*)alloc(8192ull * 4096 * 2);
  float* b0 = (float*)alloc(4096 * 4);
  float* b1 = (float*)alloc(4096 * 4);
  float* b2 = (float*)alloc(1024 * 4);

  fuse_w_kernel<<<2048, 256, 0, stream>>>(mW0, sW0, zW0, A0, (4096 * 1024) / 4);
  fuse_w_kernel<<<2048, 256, 0, stream>>>(mW1, sW1, zW1, A1, (4096 * 4096) / 4);
  fuse_w_kernel<<<2048, 256, 0, stream>>>(mW2, sW2, zW2, A2, (1024 * 4096) / 4);
  xconv_kernel<<<2048, 256, 0, stream>>>(x, xb, (8192 * 1024) / 4);
  bias_all_kernel<<<36, 256, 0, stream>>>(mb0, sb0, zb0, mb1, sb1, zb1,
                                          mb2, sb2, zb2, b0, b1, b2);

  // layer 0: [8192,1024] @ [4096,1024]^T -> relu -> h1 bf16   (BN=256, 512 wg)
  gemm_pipe_kernel<4, 1, 1><<<512, 512, 0, stream>>>(xb, A0, b0, h1,
                                                     8192, 4096, 1024, 16);
  // layer 1: [8192,4096] @ [4096,4096]^T -> relu -> h2 bf16   (BN=256, 512 wg)
  gemm_pipe_kernel<4, 1, 1><<<512, 512, 0, stream>>>(h1, A1, b1, h2,
                                                     8192, 4096, 4096, 16);
  // layer 2: [8192,4096] @ [1024,4096]^T -> d_out fp32        (BN=128, 256 wg)
  gemm_pipe_kernel<2, 0, 0><<<256, 512, 0, stream>>>(h2, A2, b2, d_out,
                                                     8192, 1024, 4096, 8);
}